// Round 9
// baseline (1564.748 us; speedup 1.0000x reference)
//
#include <hip/hip_runtime.h>
#include <math.h>

#define NE 32            // experts
#define DIM 1024         // input dim == output dim
#define NB 8192          // batch
#define F4ROW 256        // float4 per row of DIM

#define GATE_BLOCKS 512  // 16 tokens/block (4 waves x 4 tokens) — consumers
#define WSUM_BLOCKS 8192 // 4 rows/block (1 row/wave)            — producers
#define ROWS_PER_EXPERT DIM

// ---------------------------------------------------------------------------
// Single fused kernel, producer/consumer via per-expert ready counters.
//   blocks [0, GATE_BLOCKS):            gating -> spin on 2 experts -> combine
//   blocks [GATE_BLOCKS, +WSUM_BLOCKS): wsum rows + RELEASE counter add
// Producers use agent-scope release (writes back XCD L2 — the fix for the r3
// grid.sync failure); consumers use agent-scope acquire before plain reads.
// Gate blocks dispatch first so gating runs under the W stream and combines
// start as soon as *their* experts complete (staggered), not after all 32768
// rows — removing the kernel-gap serialization of the two-launch structure.
// ---------------------------------------------------------------------------
__global__ __launch_bounds__(256) void moe_fused(
    const float* __restrict__ W,     // [E, I, O]
    const float* __restrict__ x,     // [B, I]
    const float* __restrict__ gw,    // [E, I]
    const float* __restrict__ gb,    // [E]
    const float* __restrict__ bias,  // [E, I] (E,O with O==I)
    float* __restrict__ wsum,        // [E*I]            ws
    unsigned int* __restrict__ done, // [NE]             ws (zeroed per call)
    float* __restrict__ out)         // [B, I]
{
    __shared__ float gws[4 * DIM];       // one 4-expert gw tile (16 KB)
    __shared__ float logits[16][NE];     // 2 KB

    const int wave = threadIdx.x >> 6;
    const int lane = threadIdx.x & 63;

    if (blockIdx.x >= GATE_BLOCKS) {
        // ---- producer: one W row per wave (r2 measured-best shape) ----
        const int rb = blockIdx.x - GATE_BLOCKS;     // 0..8191
        const int r  = rb * 4 + wave;
        const float4* row = (const float4*)(W + (size_t)r * DIM);
        const float4 a = row[lane], b = row[lane + 64],
                     c = row[lane + 128], d = row[lane + 192];
        float s = (((a.x + a.y) + (a.z + a.w)) + ((b.x + b.y) + (b.z + b.w))) +
                  (((c.x + c.y) + (c.z + c.w)) + ((d.x + d.y) + (d.z + d.w)));
#pragma unroll
        for (int off = 32; off >= 1; off >>= 1) s += __shfl_xor(s, off, 64);
        if (lane == 0) wsum[r] = s;
        __syncthreads();                  // all 4 rows of this block stored
        if (threadIdx.x == 0) {
            // release: write back this XCD's L2 so the rows are visible
            __hip_atomic_fetch_add(&done[(rb * 4) >> 10], 4u,
                                   __ATOMIC_RELEASE, __HIP_MEMORY_SCOPE_AGENT);
        }
        return;
    }

    // ---- consumer: gating (identical to r7) ----
    const int tbase = blockIdx.x * 16 + wave * 4;

    const float4* x4 = (const float4*)x;
    float4 xq[4][4];
#pragma unroll
    for (int tk = 0; tk < 4; ++tk)
#pragma unroll
        for (int j = 0; j < 4; ++j)
            xq[tk][j] = x4[(size_t)(tbase + tk) * F4ROW + lane + 64 * j];

    const float4* gw4 = (const float4*)gw;
    float4* gws4 = (float4*)gws;

    for (int tile = 0; tile < 8; ++tile) {          // 4 experts per tile
        __syncthreads();
#pragma unroll
        for (int k = 0; k < 4; ++k) {
            const int i = threadIdx.x + 256 * k;
            gws4[i] = gw4[(size_t)tile * 1024 + i];
        }
        __syncthreads();

#pragma unroll
        for (int el = 0; el < 4; ++el) {
            const int e = tile * 4 + el;
            const float4 g0 = gws4[el * F4ROW + lane];
            const float4 g1 = gws4[el * F4ROW + lane + 64];
            const float4 g2 = gws4[el * F4ROW + lane + 128];
            const float4 g3 = gws4[el * F4ROW + lane + 192];

            float acc[4];
#pragma unroll
            for (int tk = 0; tk < 4; ++tk) {
                float v = 0.f;
                v = fmaf(xq[tk][0].x, g0.x, v); v = fmaf(xq[tk][0].y, g0.y, v);
                v = fmaf(xq[tk][0].z, g0.z, v); v = fmaf(xq[tk][0].w, g0.w, v);
                v = fmaf(xq[tk][1].x, g1.x, v); v = fmaf(xq[tk][1].y, g1.y, v);
                v = fmaf(xq[tk][1].z, g1.z, v); v = fmaf(xq[tk][1].w, g1.w, v);
                v = fmaf(xq[tk][2].x, g2.x, v); v = fmaf(xq[tk][2].y, g2.y, v);
                v = fmaf(xq[tk][2].z, g2.z, v); v = fmaf(xq[tk][2].w, g2.w, v);
                v = fmaf(xq[tk][3].x, g3.x, v); v = fmaf(xq[tk][3].y, g3.y, v);
                v = fmaf(xq[tk][3].z, g3.z, v); v = fmaf(xq[tk][3].w, g3.w, v);
                acc[tk] = v;
            }
#pragma unroll
            for (int off = 32; off >= 1; off >>= 1) {
                acc[0] += __shfl_xor(acc[0], off, 64);
                acc[1] += __shfl_xor(acc[1], off, 64);
                acc[2] += __shfl_xor(acc[2], off, 64);
                acc[3] += __shfl_xor(acc[3], off, 64);
            }
            if (lane == 0) {
                const float gbe = gb[e];
                logits[wave * 4 + 0][e] = acc[0] + gbe;
                logits[wave * 4 + 1][e] = acc[1] + gbe;
                logits[wave * 4 + 2][e] = acc[2] + gbe;
                logits[wave * 4 + 3][e] = acc[3] + gbe;
            }
        }
    }
    __syncthreads();

    // softmax + top2 on lanes 0..3 (one token each); results stay in regs
    float myv0 = 0.f, myv1 = 0.f;
    int   mye0 = 0,   mye1 = 0;
    if (lane < 4) {
        const float* L = logits[wave * 4 + lane];
        float m = L[0];
#pragma unroll
        for (int e = 1; e < NE; ++e) m = fmaxf(m, L[e]);
        float denom = 0.f;
#pragma unroll
        for (int e = 0; e < NE; ++e) denom += expf(L[e] - m);

        int e0 = 0; float l0 = L[0];
#pragma unroll
        for (int e = 1; e < NE; ++e)
            if (L[e] > l0) { l0 = L[e]; e0 = e; }
        int e1 = -1; float l1 = -INFINITY;
#pragma unroll
        for (int e = 0; e < NE; ++e)
            if (e != e0 && L[e] > l1) { l1 = L[e]; e1 = e; }

        const float inv = 1.0f / denom;
        myv0 = expf(l0 - m) * inv;
        myv1 = expf(l1 - m) * inv;
        mye0 = e0;
        mye1 = e1;
    }

    // ---- combine: per token, wait for its 2 experts, then plain f4 reads ----
    float4* o4 = (float4*)out;
#pragma unroll 1
    for (int tk = 0; tk < 4; ++tk) {
        const float v0 = __shfl(myv0, tk, 64);
        const float v1 = __shfl(myv1, tk, 64);
        const int   e0 = __shfl(mye0, tk, 64);
        const int   e1 = __shfl(mye1, tk, 64);

        // acquire: makes producers' wsum rows visible to our plain loads
        while (__hip_atomic_load(&done[e0], __ATOMIC_ACQUIRE,
                                 __HIP_MEMORY_SCOPE_AGENT) < ROWS_PER_EXPERT)
            __builtin_amdgcn_s_sleep(4);
        while (__hip_atomic_load(&done[e1], __ATOMIC_ACQUIRE,
                                 __HIP_MEMORY_SCOPE_AGENT) < ROWS_PER_EXPERT)
            __builtin_amdgcn_s_sleep(4);

        const float4* w0 = (const float4*)(wsum + (size_t)e0 * DIM);
        const float4* w1 = (const float4*)(wsum + (size_t)e1 * DIM);
        const float4* b0 = (const float4*)(bias + (size_t)e0 * DIM);
        const float4* b1 = (const float4*)(bias + (size_t)e1 * DIM);

#pragma unroll
        for (int j = 0; j < 4; ++j) {
            const int idx = lane + 64 * j;
            const float4 xv = xq[tk][j];
            const float4 a0 = w0[idx], a1 = w1[idx];
            const float4 c0 = b0[idx], c1 = b1[idx];
            float4 o;
            o.x = fmaf(v0, fmaf(xv.x, a0.x, c0.x), v1 * fmaf(xv.x, a1.x, c1.x));
            o.y = fmaf(v0, fmaf(xv.y, a0.y, c0.y), v1 * fmaf(xv.y, a1.y, c1.y));
            o.z = fmaf(v0, fmaf(xv.z, a0.z, c0.z), v1 * fmaf(xv.z, a1.z, c1.z));
            o.w = fmaf(v0, fmaf(xv.w, a0.w, c0.w), v1 * fmaf(xv.w, a1.w, c1.w));
            o4[(size_t)(tbase + tk) * F4ROW + idx] = o;
        }
    }
}

// ---------------------------------------------------------------------------
extern "C" void kernel_launch(void* const* d_in, const int* in_sizes, int n_in,
                              void* d_out, int out_size, void* d_ws, size_t ws_size,
                              hipStream_t stream) {
    const float* x    = (const float*)d_in[0];   // [B, I]
    const float* W    = (const float*)d_in[1];   // [E, I, O]
    const float* bias = (const float*)d_in[2];   // [E, O]
    const float* gw   = (const float*)d_in[3];   // [E, I]
    const float* gb   = (const float*)d_in[4];   // [E]
    // d_in[5] = topk (always 2, hardcoded)

    float*        wsum = (float*)d_ws;                              // 128 KiB
    unsigned int* done = (unsigned int*)((char*)d_ws + (size_t)NE * DIM * 4);
    float*        out  = (float*)d_out;

    // reset per-expert counters every call (replay-safe, capture-legal)
    (void)hipMemsetAsync(done, 0, NE * sizeof(unsigned int), stream);

    moe_fused<<<GATE_BLOCKS + WSUM_BLOCKS, 256, 0, stream>>>(
        W, x, gw, gb, bias, wsum, done, out);
}

// Round 10
// 59.055 us; speedup vs baseline: 26.4965x; 26.4965x over previous
//
#include <hip/hip_runtime.h>
#include <math.h>

#define NE 32            // experts
#define DIM 1024         // input dim == output dim
#define NB 8192          // batch
#define F4ROW 256        // float4 per row of DIM

#define GATE_BLOCKS 512  // 16 tokens/block (4 waves x 4 tokens)
#define WSUM_BLOCKS 2048 // persistent: 4 waves/block, 4 rows/wave (strided)
#define WSUM_WAVES  (WSUM_BLOCKS * 4)   // 8192 waves; rows = wave + it*8192

// ---------------------------------------------------------------------------
// Kernel 1: fused  (a) gating -> packed top2 per token [blocks 0..GATE_BLOCKS)
//                  (b) wsum[r] = sum_o W[r,o]           [blocks GATE_BLOCKS..)
// wsum blocks are PERSISTENT (r5/r6 counters: 13% HBM, 35% occupancy with
// 8704 one-shot blocks -> dispatch churn kept waves non-resident). 2048
// blocks = exact 8-blocks/CU residency at 18KB LDS; each wave reduces 4 rows
// strided 8192 apart, so waves stay alive and keep loads in flight.
// ---------------------------------------------------------------------------
__global__ __launch_bounds__(256) void stage1_kernel(
    const float* __restrict__ W,     // [E, I, O]
    const float* __restrict__ x,     // [B, I]
    const float* __restrict__ gw,    // [E, I]
    const float* __restrict__ gb,    // [E]
    float* __restrict__ wsum,        // [E*I]                 ws
    float4* __restrict__ topinfo)    // [B] {v0,v1,e0,e1}     ws
{
    __shared__ float gws[4 * DIM];          // one 4-expert tile of gw (16 KB)
    __shared__ float logits[16][NE];        // 2 KB

    const int wave = threadIdx.x >> 6;
    const int lane = threadIdx.x & 63;

    if (blockIdx.x >= GATE_BLOCKS) {
        // ---- persistent wsum: 4 rows per wave, stride WSUM_WAVES ----
        const int w = (blockIdx.x - GATE_BLOCKS) * 4 + wave;   // 0..8191
        const float4* W4 = (const float4*)W;
#pragma unroll 2
        for (int it = 0; it < 4; ++it) {
            const int r = w + it * WSUM_WAVES;
            const float4* row = W4 + (size_t)r * F4ROW + lane;
            const float4 a = row[0], b = row[64], c = row[128], d = row[192];
            float s = (((a.x + a.y) + (a.z + a.w)) +
                       ((b.x + b.y) + (b.z + b.w))) +
                      (((c.x + c.y) + (c.z + c.w)) +
                       ((d.x + d.y) + (d.z + d.w)));
#pragma unroll
            for (int off = 32; off >= 1; off >>= 1)
                s += __shfl_xor(s, off, 64);
            if (lane == 0) wsum[r] = s;
        }
        return;
    }

    // ---- gating: 4 tokens per wave, x rows in registers, gw via LDS tiles --
    const int tbase = blockIdx.x * 16 + wave * 4;

    const float4* x4 = (const float4*)x;
    float4 xq[4][4];
#pragma unroll
    for (int tk = 0; tk < 4; ++tk)
#pragma unroll
        for (int j = 0; j < 4; ++j)
            xq[tk][j] = x4[(size_t)(tbase + tk) * F4ROW + lane + 64 * j];

    const float4* gw4 = (const float4*)gw;
    float4* gws4 = (float4*)gws;

    for (int tile = 0; tile < 8; ++tile) {      // 4 experts per tile
        __syncthreads();                        // previous tile fully consumed
#pragma unroll
        for (int k = 0; k < 4; ++k) {
            const int i = threadIdx.x + 256 * k;
            gws4[i] = gw4[(size_t)tile * 1024 + i];
        }
        __syncthreads();

#pragma unroll
        for (int el = 0; el < 4; ++el) {
            const int e = tile * 4 + el;
            const float4 g0 = gws4[el * F4ROW + lane];
            const float4 g1 = gws4[el * F4ROW + lane + 64];
            const float4 g2 = gws4[el * F4ROW + lane + 128];
            const float4 g3 = gws4[el * F4ROW + lane + 192];

            float acc[4];
#pragma unroll
            for (int tk = 0; tk < 4; ++tk) {
                float v = 0.f;
                v = fmaf(xq[tk][0].x, g0.x, v); v = fmaf(xq[tk][0].y, g0.y, v);
                v = fmaf(xq[tk][0].z, g0.z, v); v = fmaf(xq[tk][0].w, g0.w, v);
                v = fmaf(xq[tk][1].x, g1.x, v); v = fmaf(xq[tk][1].y, g1.y, v);
                v = fmaf(xq[tk][1].z, g1.z, v); v = fmaf(xq[tk][1].w, g1.w, v);
                v = fmaf(xq[tk][2].x, g2.x, v); v = fmaf(xq[tk][2].y, g2.y, v);
                v = fmaf(xq[tk][2].z, g2.z, v); v = fmaf(xq[tk][2].w, g2.w, v);
                v = fmaf(xq[tk][3].x, g3.x, v); v = fmaf(xq[tk][3].y, g3.y, v);
                v = fmaf(xq[tk][3].z, g3.z, v); v = fmaf(xq[tk][3].w, g3.w, v);
                acc[tk] = v;
            }
#pragma unroll
            for (int off = 32; off >= 1; off >>= 1) {
                acc[0] += __shfl_xor(acc[0], off, 64);
                acc[1] += __shfl_xor(acc[1], off, 64);
                acc[2] += __shfl_xor(acc[2], off, 64);
                acc[3] += __shfl_xor(acc[3], off, 64);
            }
            if (lane == 0) {
                const float gbe = gb[e];
                logits[wave * 4 + 0][e] = acc[0] + gbe;
                logits[wave * 4 + 1][e] = acc[1] + gbe;
                logits[wave * 4 + 2][e] = acc[2] + gbe;
                logits[wave * 4 + 3][e] = acc[3] + gbe;
            }
        }
    }
    __syncthreads();

    // per-token softmax + top2 (lanes 0..3, one token each), packed float4
    if (lane < 4) {
        const int tok = tbase + lane;
        const float* L = logits[wave * 4 + lane];

        float m = L[0];
#pragma unroll
        for (int e = 1; e < NE; ++e) m = fmaxf(m, L[e]);
        float denom = 0.f;
#pragma unroll
        for (int e = 0; e < NE; ++e) denom += expf(L[e] - m);

        int e0 = 0; float l0 = L[0];
#pragma unroll
        for (int e = 1; e < NE; ++e)
            if (L[e] > l0) { l0 = L[e]; e0 = e; }
        int e1 = -1; float l1 = -INFINITY;
#pragma unroll
        for (int e = 0; e < NE; ++e)
            if (e != e0 && L[e] > l1) { l1 = L[e]; e1 = e; }

        const float inv = 1.0f / denom;
        float4 ti;
        ti.x = expf(l0 - m) * inv;
        ti.y = expf(l1 - m) * inv;
        ti.z = __int_as_float(e0);
        ti.w = __int_as_float(e1);
        topinfo[tok] = ti;
    }
}

// ---------------------------------------------------------------------------
// Kernel 2: combine.  One token per wave, 4 waves/block, 2048 blocks.
// Independent x loads first; single packed topinfo load; then the dependent
// wsum/bias row loads (256 KB hot set, L2/L3-resident).
// ---------------------------------------------------------------------------
__global__ __launch_bounds__(256) void combine_kernel(
    const float* __restrict__ x,
    const float* __restrict__ wsum,
    const float* __restrict__ bias,
    const float4* __restrict__ topinfo,
    float* __restrict__ out)
{
    const int wave = threadIdx.x >> 6;
    const int lane = threadIdx.x & 63;
    const int tok  = blockIdx.x * 4 + wave;

    const float4* x4 = (const float4*)(x + (size_t)tok * DIM);
    float4 xv[4];
#pragma unroll
    for (int j = 0; j < 4; ++j) xv[j] = x4[lane + 64 * j];

    const float4 ti = topinfo[tok];
    const float v0 = ti.x, v1 = ti.y;
    const int   e0 = __float_as_int(ti.z);
    const int   e1 = __float_as_int(ti.w);

    const float4* w0 = (const float4*)(wsum + (size_t)e0 * DIM);
    const float4* w1 = (const float4*)(wsum + (size_t)e1 * DIM);
    const float4* b0 = (const float4*)(bias + (size_t)e0 * DIM);
    const float4* b1 = (const float4*)(bias + (size_t)e1 * DIM);
    float4*       o4 = (float4*)(out + (size_t)tok * DIM);

#pragma unroll
    for (int j = 0; j < 4; ++j) {
        const int idx = lane + 64 * j;
        const float4 a0 = w0[idx], a1 = w1[idx];
        const float4 c0 = b0[idx], c1 = b1[idx];
        float4 o;
        o.x = fmaf(v0, fmaf(xv[j].x, a0.x, c0.x), v1 * fmaf(xv[j].x, a1.x, c1.x));
        o.y = fmaf(v0, fmaf(xv[j].y, a0.y, c0.y), v1 * fmaf(xv[j].y, a1.y, c1.y));
        o.z = fmaf(v0, fmaf(xv[j].z, a0.z, c0.z), v1 * fmaf(xv[j].z, a1.z, c1.z));
        o.w = fmaf(v0, fmaf(xv[j].w, a0.w, c0.w), v1 * fmaf(xv[j].w, a1.w, c1.w));
        o4[idx] = o;
    }
}

// ---------------------------------------------------------------------------
extern "C" void kernel_launch(void* const* d_in, const int* in_sizes, int n_in,
                              void* d_out, int out_size, void* d_ws, size_t ws_size,
                              hipStream_t stream) {
    const float* x    = (const float*)d_in[0];   // [B, I]
    const float* W    = (const float*)d_in[1];   // [E, I, O]
    const float* bias = (const float*)d_in[2];   // [E, O]
    const float* gw   = (const float*)d_in[3];   // [E, I]
    const float* gb   = (const float*)d_in[4];   // [E]
    // d_in[5] = topk (always 2, hardcoded)

    float*  wsum    = (float*)d_ws;                                   // 128 KiB
    float4* topinfo = (float4*)((char*)d_ws + (size_t)NE * DIM * 4);  // 128 KiB
    float*  out     = (float*)d_out;

    stage1_kernel<<<GATE_BLOCKS + WSUM_BLOCKS, 256, 0, stream>>>(
        W, x, gw, gb, wsum, topinfo);

    combine_kernel<<<NB / 4, 256, 0, stream>>>(x, wsum, bias, topinfo, out);
}